// Round 3
// baseline (213.739 us; speedup 1.0000x reference)
//
#include <hip/hip_runtime.h>
#include <hip/hip_bf16.h>

#define S_ 64
#define P_ 32
#define N_ 2048
#define H_ 64
#define E_ 64
#define D1_ 512
#define D2_ 1024
#define EPS_ 1e-5f

typedef unsigned short u16;
using bf16x8 = __attribute__((ext_vector_type(8))) __bf16;
using floatx4 = __attribute__((ext_vector_type(4))) float;

__device__ inline u16 f2bf(float x) {
    unsigned u = __float_as_uint(x);
    unsigned r = (u + 0x7fffu + ((u >> 16) & 1u)) >> 16;
    return (u16)r;
}

// ============================================================================
// Device helpers (logic verified on HW in round 9 of prior session)
// ============================================================================

// Scene prep for one (scene, d-quarter), 256 threads. Writes BN1'd A/B factors.
__device__ void prep_scene_256(int u, int tid, float* smem,
                               const float* __restrict__ pos, const float* __restrict__ h,
                               const float* __restrict__ We, const float* __restrict__ W1,
                               const float* __restrict__ g1, const float* __restrict__ be1,
                               float* __restrict__ A, float* __restrict__ Bv) {
    const int s = u >> 2, dq = u & 3;
    const int jg = tid >> 7, dl = tid & 127;   // 2 j-groups x 128 channels
    const int d = (dq << 7) + dl;
    float* hs = smem;           // 2048: h[j][e]
    float* ps = smem + 2048;    // 64: pos
    float* red = smem + 2112;   // 1024: 4 stats x 256 threads
    for (int i = tid; i < 2048; i += 256) hs[i] = h[(size_t)s * 2048 + i];
    if (tid < 64) ps[tid] = pos[s * 64 + tid];
    __syncthreads();
    float wq0 = 0.f, wq1 = 0.f;
    for (int e = 0; e < 64; ++e) {
        const float wv = W1[e * 512 + d];
        wq0 += We[e] * wv;
        wq1 += We[64 + e] * wv;
    }
    float w[16], uu[16];
#pragma unroll
    for (int jj = 0; jj < 16; ++jj) w[jj] = 0.f;
    const float4* h4 = (const float4*)hs;
    for (int e4 = 0; e4 < 16; ++e4) {
        const float c0 = W1[(64 + e4 * 4 + 0) * 512 + d];
        const float c1 = W1[(64 + e4 * 4 + 1) * 512 + d];
        const float c2 = W1[(64 + e4 * 4 + 2) * 512 + d];
        const float c3 = W1[(64 + e4 * 4 + 3) * 512 + d];
#pragma unroll
        for (int jj = 0; jj < 16; ++jj) {
            const float4 hv = h4[((jg << 4) + jj) * 16 + e4];
            w[jj] += hv.x * c0 + hv.y * c1 + hv.z * c2 + hv.w * c3;
        }
    }
    float sw = 0.f, sww = 0.f, su = 0.f, suu = 0.f;
#pragma unroll
    for (int jj = 0; jj < 16; ++jj) {
        const int j = (jg << 4) + jj;
        uu[jj] = ps[2 * j] * wq0 + ps[2 * j + 1] * wq1;
        w[jj] += uu[jj];
        sw += w[jj]; sww += w[jj] * w[jj];
        su += uu[jj]; suu += uu[jj] * uu[jj];
    }
    red[(jg << 7) + dl] = sw;
    red[256 + (jg << 7) + dl] = sww;
    red[512 + (jg << 7) + dl] = su;
    red[768 + (jg << 7) + dl] = suu;
    __syncthreads();
    const float tw = red[dl] + red[128 + dl];
    const float tww = red[256 + dl] + red[384 + dl];
    const float tu = red[512 + dl] + red[640 + dl];
    const float tuu = red[768 + dl] + red[896 + dl];
    const float mw = tw * (1.f / 32.f), mu2 = tu * (1.f / 32.f);
    const float var = (tww * (1.f / 32.f) - mw * mw) + (tuu * (1.f / 32.f) - mu2 * mu2);
    const float sc = rsqrtf(var + EPS_) * g1[d];
    const float bb = be1[d];
#pragma unroll
    for (int jj = 0; jj < 16; ++jj) {
        const int j = (jg << 4) + jj;
        A[(size_t)(s * 32 + j) * 512 + d] = (w[jj] - mw) * sc + bb;
        Bv[(size_t)(s * 32 + j) * 512 + d] = (uu[jj] - mu2) * sc;
    }
}

// W2 transpose+bf16 for one 64x64 tile, 256 threads.
__device__ void w2t_tile_256(int b2, int tid, void* smem,
                             const float* __restrict__ W2, u16* __restrict__ w2t) {
    float (*tile)[65] = (float (*)[65])smem;  // 16.6 KB
    const int bi = b2 & 15, bj = b2 >> 4;     // 16 n-tiles x 8 k-tiles
    const int tx = tid & 63, ty = tid >> 6;   // 64 x 4
#pragma unroll
    for (int i = 0; i < 64; i += 4)
        tile[ty + i][tx] = W2[(size_t)(bj * 64 + ty + i) * 1024 + bi * 64 + tx];
    __syncthreads();
#pragma unroll
    for (int i = 0; i < 64; i += 4)
        w2t[(size_t)(bi * 64 + ty + i) * 512 + bj * 64 + tx] = f2bf(tile[tx][ty + i]);
}

// ============================================================================
// k_gemm helpers: 256x256 tile, 8 waves (2M x 4N), 2 phases per K-tile.
// ============================================================================

__device__ __forceinline__ void ld4x4(float4 d[4], const float* __restrict__ p) {
    d[0] = *(const float4*)(p);
    d[1] = *(const float4*)(p + 4);
    d[2] = *(const float4*)(p + 8);
    d[3] = *(const float4*)(p + 12);
}

// relu(a-b) -> bf16, 16 elems = 2 chunks, written to XOR-swizzled positions.
__device__ __forceinline__ void build_half(u16* __restrict__ AsN, int rowb,
                                           int posA, int posB,
                                           const float4 a[4], const float4 b[4]) {
    bf16x8 o;
    o[0] = (__bf16)fmaxf(a[0].x - b[0].x, 0.f);
    o[1] = (__bf16)fmaxf(a[0].y - b[0].y, 0.f);
    o[2] = (__bf16)fmaxf(a[0].z - b[0].z, 0.f);
    o[3] = (__bf16)fmaxf(a[0].w - b[0].w, 0.f);
    o[4] = (__bf16)fmaxf(a[1].x - b[1].x, 0.f);
    o[5] = (__bf16)fmaxf(a[1].y - b[1].y, 0.f);
    o[6] = (__bf16)fmaxf(a[1].z - b[1].z, 0.f);
    o[7] = (__bf16)fmaxf(a[1].w - b[1].w, 0.f);
    *(bf16x8*)(AsN + rowb + posA) = o;
    bf16x8 p;
    p[0] = (__bf16)fmaxf(a[2].x - b[2].x, 0.f);
    p[1] = (__bf16)fmaxf(a[2].y - b[2].y, 0.f);
    p[2] = (__bf16)fmaxf(a[2].z - b[2].z, 0.f);
    p[3] = (__bf16)fmaxf(a[2].w - b[2].w, 0.f);
    p[4] = (__bf16)fmaxf(a[3].x - b[3].x, 0.f);
    p[5] = (__bf16)fmaxf(a[3].y - b[3].y, 0.f);
    p[6] = (__bf16)fmaxf(a[3].z - b[3].z, 0.f);
    p[7] = (__bf16)fmaxf(a[3].w - b[3].w, 0.f);
    *(bf16x8*)(AsN + rowb + posB) = p;
}

// Stage one 128-row half of the Ws K-tile via global_load_lds (pre-swizzled src).
__device__ __forceinline__ void stage_ws(const u16* __restrict__ w2t, u16* WsN,
                                         int N0, int kcol, int h, int wave,
                                         int lrow, int gchk) {
#pragma unroll
    for (int c = 0; c < 2; ++c) {
        const int rbase = h * 128 + wave * 16 + c * 8;
        const u16* gb = w2t + (size_t)(N0 + rbase + lrow) * 512 + kcol + gchk * 8;
        __builtin_amdgcn_global_load_lds(
            (const __attribute__((address_space(1))) void*)gb,
            (__attribute__((address_space(3))) void*)(WsN + rbase * 64), 16, 0, 0);
    }
}

// One k-chunk (K=32) worth of fragments for the whole wave tile: 12 x b128.
__device__ __forceinline__ void read_all(bf16x8 af[8], bf16x8 wf[4],
                                         const u16* __restrict__ Ab,
                                         const u16* __restrict__ Wb,
                                         int wm, int wn, int l16, int pos) {
#pragma unroll
    for (int i = 0; i < 8; ++i)
        af[i] = *(const bf16x8*)(Ab + (wm * 128 + i * 16 + l16) * 64 + pos);
#pragma unroll
    for (int n = 0; n < 4; ++n)
        wf[n] = *(const bf16x8*)(Wb + (wn * 64 + n * 16 + l16) * 64 + pos);
}

// 32 MFMA covering the full 128x64 wave tile for one k-chunk.
__device__ __forceinline__ void mfma_all(floatx4 (&acc)[8][4],
                                         const bf16x8 af[8], const bf16x8 wf[4]) {
#pragma unroll
    for (int i = 0; i < 8; ++i)
#pragma unroll
        for (int n = 0; n < 4; ++n)
            acc[i][n] = __builtin_amdgcn_mfma_f32_16x16x32_bf16(
                af[i], wf[n], acc[i][n], 0, 0, 0);
}

#define LGKM0() asm volatile("s_waitcnt lgkmcnt(0)" ::: "memory")
#define VM0()   asm volatile("s_waitcnt vmcnt(0)" ::: "memory")
#define VMC12() asm volatile("s_waitcnt vmcnt(12)" ::: "memory")

// Phase tail: bar -> lgkm0 -> fence -> prio1 -> 32 MFMA -> prio0 -> bar.
#define PHASE_TAIL()                                                  \
    __builtin_amdgcn_s_barrier();                                     \
    LGKM0();                                                          \
    __builtin_amdgcn_sched_barrier(0);                                \
    __builtin_amdgcn_s_setprio(1);                                    \
    mfma_all(acc, af, wf);                                            \
    __builtin_amdgcn_s_setprio(0);                                    \
    __builtin_amdgcn_s_barrier();

// ============================================================================
// Fused GEMM: block = 256 rows (one scene's 8 k-peds x 32 j) x 256 cols.
// K = 512 = 8 tiles of 64. Double-buffered LDS (128 KB).
// Round-3 restructure: fragments read ONCE per k-chunk (12 b128 per 32 MFMA,
// 2.67 MFMA/read vs round-2's 1.33) -- LDS read BW was the measured cap.
// Pipeline per tile t (2 phases):
//   P0: stage Ws(t+1) [4 gload_lds, 3-phase flight]; read k0 frags;
//       build As(t+1) h0 (auto-vmcnt leaves stages in flight); 32 MFMA.
//   P1: read k1 frags; build As(t+1) h1; issue AB(t+2) regs [12 loads];
//       vmcnt(12) = counted drain of Ws(t+1) stages only; 32 MFMA.
// ============================================================================
__global__ __launch_bounds__(512, 2)
void k_gemm(const float* __restrict__ A, const float* __restrict__ Bv,
            const u16* __restrict__ w2t,
            float* __restrict__ maxv, float* __restrict__ minv,
            float* __restrict__ psum, float* __restrict__ psumsq) {
    extern __shared__ __align__(16) char lds_raw[];
    u16* AsB = (u16*)lds_raw;       // [2][256][64] bf16 = 64 KB
    u16* WsB = AsB + 32768;         // [2][256][64] bf16 = 64 KB

    const int tid = threadIdx.x;
    const int wave = tid >> 6, lane = tid & 63;
    const int wm = wave >> 2, wn = wave & 3;          // 2M x 4N wave grid
    const int quad = lane >> 4, l16 = lane & 15;
    const int lrow = lane >> 3, gchk = (lane & 7) ^ lrow;

    const int bid = blockIdx.x;
    const int mb = bid >> 2, nb = bid & 3;
    const int s = mb >> 2, kq = mb & 3;               // scene, ped-quarter
    const int N0 = nb << 8;

    // As-build indexing: thread -> (row-in-half, 16-elem k-group)
    const int brow = tid >> 2, kq4 = tid & 3;
    const int j0 = brow & 31, pl0 = brow >> 5;
    const float* Arow = A + ((size_t)(s * 32 + j0) << 9) + (kq4 << 4);
    const float* Brow0 = Bv + ((size_t)(s * 32 + kq * 8 + pl0) << 9) + (kq4 << 4);
    const float* Brow1 = Brow0 + (4 << 9);            // peds 4..7 of this quarter
    const int posA = ((kq4 * 2) ^ (brow & 7)) << 3;
    const int posB = ((kq4 * 2 + 1) ^ (brow & 7)) << 3;
    const int rowb0 = brow * 64;
    const int rowb1 = (128 + brow) * 64;

    // fragment k-chunk positions (XOR swizzle, row&7 == l16&7)
    const int posk0 = ((quad) ^ (l16 & 7)) << 3;
    const int posk1 = ((4 + quad) ^ (l16 & 7)) << 3;

    floatx4 acc[8][4] = {};
    float4 xa[4], xb[4], yb[4];

    // ---- prologue: AB(0) -> build As(0); stage Ws(0); preload AB(1);
    //      counted wait (12 AB(1) loads stay in flight); barrier ----
    {
        ld4x4(xa, Arow); ld4x4(xb, Brow0); ld4x4(yb, Brow1);
        stage_ws(w2t, WsB, N0, 0, 0, wave, lrow, gchk);
        stage_ws(w2t, WsB, N0, 0, 1, wave, lrow, gchk);
        build_half(AsB, rowb0, posA, posB, xa, xb);
        build_half(AsB, rowb1, posA, posB, xa, yb);
        ld4x4(xa, Arow + 64); ld4x4(xb, Brow0 + 64); ld4x4(yb, Brow1 + 64);
        VMC12();
        LGKM0();
        __builtin_amdgcn_s_barrier();
    }

    for (int t = 0; t < 8; ++t) {
        const int buf = t & 1;
        const u16* Ab = AsB + (buf << 14);
        const u16* Wb = WsB + (buf << 14);
        u16* AsN = AsB + ((buf ^ 1) << 14);
        u16* WsN = WsB + ((buf ^ 1) << 14);
        const bool pf = (t < 7);
        const int kn = (t + 1) << 6;
        bf16x8 af[8], wf[4];

        // -------- P0: k-chunk 0; stage Ws(t+1); build As(t+1) h0 -----------
        if (pf) {
            stage_ws(w2t, WsN, N0, kn, 0, wave, lrow, gchk);
            stage_ws(w2t, WsN, N0, kn, 1, wave, lrow, gchk);
        }
        read_all(af, wf, Ab, Wb, wm, wn, l16, posk0);
        if (pf) build_half(AsN, rowb0, posA, posB, xa, xb);
        PHASE_TAIL()

        // -------- P1: k-chunk 1; build As(t+1) h1; issue AB(t+2) -----------
        read_all(af, wf, Ab, Wb, wm, wn, l16, posk1);
        if (pf) build_half(AsN, rowb1, posA, posB, xa, yb);
        if (t < 6) {
            const int kn2 = (t + 2) << 6;
            ld4x4(xa, Arow + kn2); ld4x4(xb, Brow0 + kn2); ld4x4(yb, Brow1 + kn2);
            VMC12();
        } else {
            VM0();  // tail tiles: only remaining stages outstanding
        }
        PHASE_TAIL()
    }

    // ---- epilogue: j-max/min per ped + BN2 partial sums (registers only) ----
#pragma unroll
    for (int tn = 0; tn < 4; ++tn) {
        const int col = N0 + wn * 64 + tn * 16 + l16;
        float wsum = 0.f, wsq = 0.f;
#pragma unroll
        for (int e = 0; e < 4; ++e) {
            float vmax = -3.4e38f, vmin = 3.4e38f, vs = 0.f, vq = 0.f;
#pragma unroll
            for (int tm = e * 2; tm < e * 2 + 2; ++tm)
#pragma unroll
                for (int r = 0; r < 4; ++r) {
                    const float v = acc[tm][tn][r];
                    vmax = fmaxf(vmax, v);
                    vmin = fminf(vmin, v);
                    vs += v;
                    vq += v * v;
                }
#pragma unroll
            for (int off = 16; off < 64; off <<= 1) {
                vmax = fmaxf(vmax, __shfl_xor(vmax, off));
                vmin = fminf(vmin, __shfl_xor(vmin, off));
                vs += __shfl_xor(vs, off);
                vq += __shfl_xor(vq, off);
            }
            if (quad == 0) {
                const int kg = s * 32 + kq * 8 + wm * 4 + e;
                maxv[(size_t)kg * 1024 + col] = vmax;
                minv[(size_t)kg * 1024 + col] = vmin;
            }
            wsum += vs;
            wsq += vq;
        }
        if (quad == 0) {
            const int slot = ((s * 4 + kq) << 1) + wm;  // 8 per scene
            psum[(size_t)slot * 1024 + col] = wsum;
            psumsq[(size_t)slot * 1024 + col] = wsq;
        }
    }
}

// ============================================================================
// Prep / final kernels
// ============================================================================
__global__ __launch_bounds__(256)
void k_prep(const float* __restrict__ pos, const float* __restrict__ h,
            const float* __restrict__ We, const float* __restrict__ W1,
            const float* __restrict__ g1, const float* __restrict__ be1,
            const float* __restrict__ W2,
            float* __restrict__ A, float* __restrict__ Bv, u16* __restrict__ w2t) {
    __shared__ __align__(16) char smem_raw[16912];
    const int bid = blockIdx.x;
    if (bid < 256)
        prep_scene_256(bid, threadIdx.x, (float*)smem_raw, pos, h, We, W1, g1, be1, A, Bv);
    else
        w2t_tile_256(bid - 256, threadIdx.x, smem_raw, W2, w2t);
}

__global__ __launch_bounds__(256)
void k_final(const float* __restrict__ maxv, const float* __restrict__ minv,
             const float* __restrict__ psum, const float* __restrict__ psumsq,
             const float* __restrict__ g2, const float* __restrict__ be2,
             float* __restrict__ out) {
    const int u = blockIdx.x, tid = threadIdx.x;
    const int s3 = u >> 2;
    const int c = ((u & 3) << 8) + tid;
    float sm = 0.f, sq = 0.f;
#pragma unroll
    for (int t = 0; t < 8; ++t) {
        sm += psum[(size_t)(s3 * 8 + t) * 1024 + c];
        sq += psumsq[(size_t)(s3 * 8 + t) * 1024 + c];
    }
    const float mu = sm * (1.f / 1024.f);
    const float var = sq * (1.f / 1024.f) - mu * mu;
    const float inv = rsqrtf(var + EPS_);
    const float scale = g2[c] * inv;
    const float bb = be2[c];
    const float* src = (scale >= 0.f) ? maxv : minv;  // BN monotone direction
    for (int k = 0; k < 32; ++k) {
        const float v = src[(size_t)(s3 * 32 + k) * 1024 + c];
        out[(size_t)(s3 * 32 + k) * 1024 + c] = fmaxf((v - mu) * scale + bb, 0.f);
    }
}

extern "C" void kernel_launch(void* const* d_in, const int* in_sizes, int n_in,
                              void* d_out, int out_size, void* d_ws, size_t ws_size,
                              hipStream_t stream) {
    const float* h_states = (const float*)d_in[0];
    const float* end_pos = (const float*)d_in[2];
    const float* W_embed = (const float*)d_in[4];
    const float* W1 = (const float*)d_in[6];
    const float* g1 = (const float*)d_in[8];
    const float* be1 = (const float*)d_in[9];
    const float* W2 = (const float*)d_in[10];
    const float* g2 = (const float*)d_in[12];
    const float* be2 = (const float*)d_in[13];
    float* out = (float*)d_out;

    float* Abuf = (float*)d_ws;                // 1,048,576 f
    float* Bbuf = Abuf + 1048576;              // 1,048,576 f
    float* maxv = Bbuf + 1048576;              // 2,097,152 f
    float* minv = maxv + 2097152;              // 2,097,152 f
    float* psum = minv + 2097152;              // 524,288 f used (1M reserved)
    float* psumsq = psum + 1048576;            // 524,288 f used (1M reserved)
    u16* w2t = (u16*)(psumsq + 1048576);       // 524,288 u16

    static int lds_opt_in = 0;
    if (!lds_opt_in) {
        hipFuncSetAttribute(reinterpret_cast<const void*>(k_gemm),
                            hipFuncAttributeMaxDynamicSharedMemorySize, 131072);
        lds_opt_in = 1;
    }

    k_prep<<<dim3(384), dim3(256), 0, stream>>>(end_pos, h_states, W_embed, W1,
                                                g1, be1, W2, Abuf, Bbuf, w2t);
    k_gemm<<<dim3(1024), dim3(512), 131072, stream>>>(Abuf, Bbuf, w2t, maxv, minv,
                                                      psum, psumsq);
    k_final<<<dim3(256), dim3(256), 0, stream>>>(maxv, minv, psum, psumsq, g2, be2, out);
}

// Round 5
// 186.484 us; speedup vs baseline: 1.1462x; 1.1462x over previous
//
#include <hip/hip_runtime.h>
#include <hip/hip_bf16.h>

#define S_ 64
#define P_ 32
#define N_ 2048
#define H_ 64
#define E_ 64
#define D1_ 512
#define D2_ 1024
#define EPS_ 1e-5f

typedef unsigned short u16;
using bf16x8 = __attribute__((ext_vector_type(8))) __bf16;
using floatx4 = __attribute__((ext_vector_type(4))) float;

__device__ inline u16 f2bf(float x) {
    unsigned u = __float_as_uint(x);
    unsigned r = (u + 0x7fffu + ((u >> 16) & 1u)) >> 16;
    return (u16)r;
}

// ============================================================================
// Device helpers (logic verified on HW in round 9 of prior session)
// ============================================================================

// Scene prep for one (scene, d-quarter), 256 threads. Writes BN1'd A/B factors.
__device__ void prep_scene_256(int u, int tid, float* smem,
                               const float* __restrict__ pos, const float* __restrict__ h,
                               const float* __restrict__ We, const float* __restrict__ W1,
                               const float* __restrict__ g1, const float* __restrict__ be1,
                               float* __restrict__ A, float* __restrict__ Bv) {
    const int s = u >> 2, dq = u & 3;
    const int jg = tid >> 7, dl = tid & 127;   // 2 j-groups x 128 channels
    const int d = (dq << 7) + dl;
    float* hs = smem;           // 2048: h[j][e]
    float* ps = smem + 2048;    // 64: pos
    float* red = smem + 2112;   // 1024: 4 stats x 256 threads
    for (int i = tid; i < 2048; i += 256) hs[i] = h[(size_t)s * 2048 + i];
    if (tid < 64) ps[tid] = pos[s * 64 + tid];
    __syncthreads();
    float wq0 = 0.f, wq1 = 0.f;
    for (int e = 0; e < 64; ++e) {
        const float wv = W1[e * 512 + d];
        wq0 += We[e] * wv;
        wq1 += We[64 + e] * wv;
    }
    float w[16], uu[16];
#pragma unroll
    for (int jj = 0; jj < 16; ++jj) w[jj] = 0.f;
    const float4* h4 = (const float4*)hs;
    for (int e4 = 0; e4 < 16; ++e4) {
        const float c0 = W1[(64 + e4 * 4 + 0) * 512 + d];
        const float c1 = W1[(64 + e4 * 4 + 1) * 512 + d];
        const float c2 = W1[(64 + e4 * 4 + 2) * 512 + d];
        const float c3 = W1[(64 + e4 * 4 + 3) * 512 + d];
#pragma unroll
        for (int jj = 0; jj < 16; ++jj) {
            const float4 hv = h4[((jg << 4) + jj) * 16 + e4];
            w[jj] += hv.x * c0 + hv.y * c1 + hv.z * c2 + hv.w * c3;
        }
    }
    float sw = 0.f, sww = 0.f, su = 0.f, suu = 0.f;
#pragma unroll
    for (int jj = 0; jj < 16; ++jj) {
        const int j = (jg << 4) + jj;
        uu[jj] = ps[2 * j] * wq0 + ps[2 * j + 1] * wq1;
        w[jj] += uu[jj];
        sw += w[jj]; sww += w[jj] * w[jj];
        su += uu[jj]; suu += uu[jj] * uu[jj];
    }
    red[(jg << 7) + dl] = sw;
    red[256 + (jg << 7) + dl] = sww;
    red[512 + (jg << 7) + dl] = su;
    red[768 + (jg << 7) + dl] = suu;
    __syncthreads();
    const float tw = red[dl] + red[128 + dl];
    const float tww = red[256 + dl] + red[384 + dl];
    const float tu = red[512 + dl] + red[640 + dl];
    const float tuu = red[768 + dl] + red[896 + dl];
    const float mw = tw * (1.f / 32.f), mu2 = tu * (1.f / 32.f);
    const float var = (tww * (1.f / 32.f) - mw * mw) + (tuu * (1.f / 32.f) - mu2 * mu2);
    const float sc = rsqrtf(var + EPS_) * g1[d];
    const float bb = be1[d];
#pragma unroll
    for (int jj = 0; jj < 16; ++jj) {
        const int j = (jg << 4) + jj;
        A[(size_t)(s * 32 + j) * 512 + d] = (w[jj] - mw) * sc + bb;
        Bv[(size_t)(s * 32 + j) * 512 + d] = (uu[jj] - mu2) * sc;
    }
}

// W2 transpose+bf16 for one 64x64 tile, 256 threads.
__device__ void w2t_tile_256(int b2, int tid, void* smem,
                             const float* __restrict__ W2, u16* __restrict__ w2t) {
    float (*tile)[65] = (float (*)[65])smem;  // 16.6 KB
    const int bi = b2 & 15, bj = b2 >> 4;     // 16 n-tiles x 8 k-tiles
    const int tx = tid & 63, ty = tid >> 6;   // 64 x 4
#pragma unroll
    for (int i = 0; i < 64; i += 4)
        tile[ty + i][tx] = W2[(size_t)(bj * 64 + ty + i) * 1024 + bi * 64 + tx];
    __syncthreads();
#pragma unroll
    for (int i = 0; i < 64; i += 4)
        w2t[(size_t)(bi * 64 + ty + i) * 512 + bj * 64 + tx] = f2bf(tile[tx][ty + i]);
}

#define LGKM0() asm volatile("s_waitcnt lgkmcnt(0)" ::: "memory")
#define VMC8()  asm volatile("s_waitcnt vmcnt(8)" ::: "memory")
#define VM0()   asm volatile("s_waitcnt vmcnt(0)" ::: "memory")

// ============================================================================
// Fused GEMM: round-0 proven structure (block = 128 rows = 4 peds x 32 j,
// 256 threads, 2 blocks/CU) + ONE change: Ws double-buffered with counted
// vmcnt(8) so the per-tile global_load_lds drain (round-0's __syncthreads
// vmcnt(0)) never stalls. Tiles linearized u = cs*8+it; Ws(u+1) staged into
// the back buffer right after the As build, giving it the whole MFMA phase
// plus the next build (~700+ cyc) of flight. LDS 16KB As + 2x32KB Ws = 80KB
// -> exactly 2 blocks/CU. R5-proven swizzles verbatim.
// ============================================================================
__global__ __launch_bounds__(256, 2)
void k_gemm(const float* __restrict__ A, const float* __restrict__ Bv,
            const u16* __restrict__ w2t,
            float* __restrict__ maxv, float* __restrict__ minv,
            float* __restrict__ psum, float* __restrict__ psumsq) {
    extern __shared__ __align__(16) char lds_raw[];
    u16* As = (u16*)lds_raw;        // 128 x 64 bf16 = 16 KB
    u16* Ws = As + 8192;            // [2][256][64] bf16 = 64 KB

    const int tid = threadIdx.x;
    const int wave = tid >> 6, lane = tid & 63;
    const int wm = wave >> 1, wn = wave & 1;
    const int quad = lane >> 4, l16 = lane & 15;
    const int lrow = lane >> 3, lchk = lane & 7;
    const int gchk = lchk ^ lrow;
    const int sj = tid >> 3, sc8 = tid & 7;
    const int mt = blockIdx.x;
    const int s2 = mt >> 3, rb = mt & 7;
    const int pedb = rb << 2;
    const float* Aj = A + ((size_t)(s2 * 32 + sj) << 9) + (sc8 << 3);
    const float* Bp = Bv + ((size_t)(s2 * 32 + pedb) << 9) + (sc8 << 3);
    const int swz = (sc8 ^ (sj & 7)) << 3;

    floatx4 acc[4][8] = {};

    // prologue: stage Ws(u=0) into buffer 0
    {
#pragma unroll
        for (int t = 0; t < 8; ++t) {
            const int rbase = (wave << 6) + (t << 3);
            const u16* gb = w2t + (size_t)(rbase + lrow) * 512 + (gchk << 3);
            __builtin_amdgcn_global_load_lds(
                (const __attribute__((address_space(1))) void*)gb,
                (__attribute__((address_space(3))) void*)(Ws + (rbase << 6)), 16, 0, 0);
        }
    }

    for (int u = 0; u < 32; ++u) {
        const int cs = u >> 3, it = u & 7;
        const int k0 = it << 6, N0 = cs << 8;
        const int buf = u & 1;
        const u16* Wcur = Ws + (buf << 14);
        u16* Wnxt = Ws + ((buf ^ 1) << 14);

        // ---- build As(it): per-lane relu-diff, native bf16 cvt (R3/R7) ----
        {
            const float4 alo = *(const float4*)(Aj + k0);
            const float4 ahi = *(const float4*)(Aj + k0 + 4);
#pragma unroll
            for (int p = 0; p < 4; ++p) {
                const int r = (p << 5) + sj;
                const float4 blo = *(const float4*)(Bp + ((size_t)p << 9) + k0);
                const float4 bhi = *(const float4*)(Bp + ((size_t)p << 9) + k0 + 4);
                bf16x8 o;
                o[0] = (__bf16)fmaxf(alo.x - blo.x, 0.f);
                o[1] = (__bf16)fmaxf(alo.y - blo.y, 0.f);
                o[2] = (__bf16)fmaxf(alo.z - blo.z, 0.f);
                o[3] = (__bf16)fmaxf(alo.w - blo.w, 0.f);
                o[4] = (__bf16)fmaxf(ahi.x - bhi.x, 0.f);
                o[5] = (__bf16)fmaxf(ahi.y - bhi.y, 0.f);
                o[6] = (__bf16)fmaxf(ahi.z - bhi.z, 0.f);
                o[7] = (__bf16)fmaxf(ahi.w - bhi.w, 0.f);
                *(bf16x8*)(As + (r << 6) + swz) = o;
            }
        }

        // ---- stage Ws(u+1) into back buffer; counted drain of Ws(u) ----
        if (u < 31) {
            const int cs1 = (u + 1) >> 3, it1 = (u + 1) & 7;
            const int kn = it1 << 6, Nn = cs1 << 8;
#pragma unroll
            for (int t = 0; t < 8; ++t) {
                const int rbase = (wave << 6) + (t << 3);
                const u16* gb = w2t + (size_t)(Nn + rbase + lrow) * 512 + (kn + (gchk << 3));
                __builtin_amdgcn_global_load_lds(
                    (const __attribute__((address_space(1))) void*)gb,
                    (__attribute__((address_space(3))) void*)(Wnxt + (rbase << 6)), 16, 0, 0);
            }
            VMC8();   // >=8 newest (Ws(u+1)) may fly; Ws(u) + As-src loads retired
        } else {
            VM0();    // last tile: drain everything
        }
        LGKM0();      // this wave's As ds_writes visible
        __builtin_amdgcn_s_barrier();

        // ---- MFMA: 64 MFMA from As + Wcur (R5 swizzled reads) ----
#pragma unroll
        for (int kk = 0; kk < 2; ++kk) {
            const int ck = (kk << 2) + quad;
            const int po = (ck ^ (l16 & 7)) << 3;
            bf16x8 af[4], wf[8];
#pragma unroll
            for (int tm = 0; tm < 4; ++tm) {
                const int row = (wm << 6) + (tm << 4) + l16;
                af[tm] = *(const bf16x8*)(As + (row << 6) + po);
            }
#pragma unroll
            for (int tn = 0; tn < 8; ++tn) {
                const int wrow = (wn << 7) + (tn << 4) + l16;
                wf[tn] = *(const bf16x8*)(Wcur + (wrow << 6) + ((ck ^ (wrow & 7)) << 3));
            }
#pragma unroll
            for (int tm = 0; tm < 4; ++tm)
#pragma unroll
                for (int tn = 0; tn < 8; ++tn)
                    acc[tm][tn] = __builtin_amdgcn_mfma_f32_16x16x32_bf16(
                        af[tm], wf[tn], acc[tm][tn], 0, 0, 0);
        }
        __builtin_amdgcn_s_barrier();

        // ---- epilogue at end of each col-split: j-max/min + BN2 partials ----
        if (it == 7) {
#pragma unroll
            for (int tn = 0; tn < 8; ++tn) {
                const int col = N0 + (wn << 7) + (tn << 4) + l16;
                float wsum = 0.f, wsq = 0.f;
#pragma unroll
                for (int gp = 0; gp < 2; ++gp) {
                    float vmax = -3.4e38f, vmin = 3.4e38f, vs = 0.f, vq = 0.f;
#pragma unroll
                    for (int tm = gp * 2; tm < gp * 2 + 2; ++tm)
#pragma unroll
                        for (int r = 0; r < 4; ++r) {
                            const float v = acc[tm][tn][r];
                            vmax = fmaxf(vmax, v);
                            vmin = fminf(vmin, v);
                            vs += v;
                            vq += v * v;
                        }
#pragma unroll
                    for (int off = 16; off < 64; off <<= 1) {
                        vmax = fmaxf(vmax, __shfl_xor(vmax, off));
                        vmin = fminf(vmin, __shfl_xor(vmin, off));
                        vs += __shfl_xor(vs, off);
                        vq += __shfl_xor(vq, off);
                    }
                    if (quad == 0) {
                        const int kg = s2 * 32 + pedb + (wm << 1) + gp;
                        maxv[(size_t)kg * 1024 + col] = vmax;
                        minv[(size_t)kg * 1024 + col] = vmin;
                    }
                    wsum += vs;
                    wsq += vq;
                }
                if (quad == 0) {
                    const int slot = (s2 << 4) + (rb << 1) + wm;  // 16 per scene
                    psum[(size_t)slot * 1024 + col] = wsum;
                    psumsq[(size_t)slot * 1024 + col] = wsq;
                }
            }
            // reset accumulator for next col-split
#pragma unroll
            for (int tm = 0; tm < 4; ++tm)
#pragma unroll
                for (int tn = 0; tn < 8; ++tn)
                    acc[tm][tn] = floatx4{0.f, 0.f, 0.f, 0.f};
        }
    }
}

// ============================================================================
// Prep / final kernels
// ============================================================================
__global__ __launch_bounds__(256)
void k_prep(const float* __restrict__ pos, const float* __restrict__ h,
            const float* __restrict__ We, const float* __restrict__ W1,
            const float* __restrict__ g1, const float* __restrict__ be1,
            const float* __restrict__ W2,
            float* __restrict__ A, float* __restrict__ Bv, u16* __restrict__ w2t) {
    __shared__ __align__(16) char smem_raw[16912];
    const int bid = blockIdx.x;
    if (bid < 256)
        prep_scene_256(bid, threadIdx.x, (float*)smem_raw, pos, h, We, W1, g1, be1, A, Bv);
    else
        w2t_tile_256(bid - 256, threadIdx.x, smem_raw, W2, w2t);
}

__global__ __launch_bounds__(256)
void k_final(const float* __restrict__ maxv, const float* __restrict__ minv,
             const float* __restrict__ psum, const float* __restrict__ psumsq,
             const float* __restrict__ g2, const float* __restrict__ be2,
             float* __restrict__ out) {
    const int u = blockIdx.x, tid = threadIdx.x;
    const int s3 = u >> 2;
    const int c = ((u & 3) << 8) + tid;
    float sm = 0.f, sq = 0.f;
#pragma unroll
    for (int t = 0; t < 16; ++t) {
        sm += psum[(size_t)(s3 * 16 + t) * 1024 + c];
        sq += psumsq[(size_t)(s3 * 16 + t) * 1024 + c];
    }
    const float mu = sm * (1.f / 1024.f);
    const float var = sq * (1.f / 1024.f) - mu * mu;
    const float inv = rsqrtf(var + EPS_);
    const float scale = g2[c] * inv;
    const float bb = be2[c];
    const float* src = (scale >= 0.f) ? maxv : minv;  // BN monotone direction
    for (int k = 0; k < 32; ++k) {
        const float v = src[(size_t)(s3 * 32 + k) * 1024 + c];
        out[(size_t)(s3 * 32 + k) * 1024 + c] = fmaxf((v - mu) * scale + bb, 0.f);
    }
}

extern "C" void kernel_launch(void* const* d_in, const int* in_sizes, int n_in,
                              void* d_out, int out_size, void* d_ws, size_t ws_size,
                              hipStream_t stream) {
    const float* h_states = (const float*)d_in[0];
    const float* end_pos = (const float*)d_in[2];
    const float* W_embed = (const float*)d_in[4];
    const float* W1 = (const float*)d_in[6];
    const float* g1 = (const float*)d_in[8];
    const float* be1 = (const float*)d_in[9];
    const float* W2 = (const float*)d_in[10];
    const float* g2 = (const float*)d_in[12];
    const float* be2 = (const float*)d_in[13];
    float* out = (float*)d_out;

    float* Abuf = (float*)d_ws;                // 1,048,576 f
    float* Bbuf = Abuf + 1048576;              // 1,048,576 f
    float* maxv = Bbuf + 1048576;              // 2,097,152 f
    float* minv = maxv + 2097152;              // 2,097,152 f
    float* psum = minv + 2097152;              // 1,048,576 f
    float* psumsq = psum + 1048576;            // 1,048,576 f
    u16* w2t = (u16*)(psumsq + 1048576);       // 524,288 u16

    static int lds_opt_in = 0;
    if (!lds_opt_in) {
        hipFuncSetAttribute(reinterpret_cast<const void*>(k_gemm),
                            hipFuncAttributeMaxDynamicSharedMemorySize, 81920);
        lds_opt_in = 1;
    }

    k_prep<<<dim3(384), dim3(256), 0, stream>>>(end_pos, h_states, W_embed, W1,
                                                g1, be1, W2, Abuf, Bbuf, w2t);
    k_gemm<<<dim3(512), dim3(256), 81920, stream>>>(Abuf, Bbuf, w2t, maxv, minv,
                                                    psum, psumsq);
    k_final<<<dim3(256), dim3(256), 0, stream>>>(maxv, minv, psum, psumsq, g2, be2, out);
}